// Round 16
// baseline (203.078 us; speedup 1.0000x reference)
//
#include <hip/hip_runtime.h>
#include <hip/hip_bf16.h>

#define S 64
#define B 32
#define HID 16
#define EMB 32
#define V 50257
#define NCB 197                 // pass1 column blocks of 256 cols (50432 scanned)
#define NCG2 66                 // pass2 column groups
#define CPG2 3                  // 256-col chunks per group (Wb slice in registers)
#define VP5 (NCG2*CPG2*256)     // 50688 padded cols
#define M 2048                  // S*B rows
#define PREP_BLOCKS (VP5*EMB/256)   // 6336 exactly
#define NRG 8                   // row groups for pass1
#define RT_PER (128/NRG)
#define RTPB 16                 // pass2: row-tiles per block (256 rows)

using bf16x8 = __attribute__((ext_vector_type(8))) __bf16;
using f32x4  = __attribute__((ext_vector_type(4))) float;

// ---------------- K1: fused prep ---------------------------------------------------
__global__ void k_prep(const float* __restrict__ W_ho, const float* __restrict__ b_ho,
                       const int* __restrict__ idx, const float* __restrict__ emb,
                       const float* __restrict__ W_lr, const float* __restrict__ b_lr,
                       const float* __restrict__ W_rl, const float* __restrict__ b_rl,
                       __bf16* __restrict__ Wb, float* __restrict__ bias,
                       float* __restrict__ P) {
    const int bx = blockIdx.x;
    if (bx < PREP_BLOCKS) {
        int i = bx * 256 + threadIdx.x;          // < VP5*EMB exactly
        if (i < VP5) bias[i] = (i < V) ? b_ho[i] : -1e30f;
        int v = i >> 5;
        Wb[i] = (v < V) ? (__bf16)W_ho[i] : (__bf16)0.f;
    } else {
        int i = (bx - PREP_BLOCKS) * 256 + threadIdx.x;   // 0..65535
        const int dir = i >> 15, r = i & 32767, m = r >> 4, j = r & 15;
        const float* W  = dir ? W_rl : W_lr;
        const float* bb = dir ? b_rl : b_lr;
        const int tok = idx[m];
        const float4* er = reinterpret_cast<const float4*>(emb + (size_t)tok * EMB);
        const float4* wr = reinterpret_cast<const float4*>(W + j * (EMB + HID));
        float acc = bb[j];
        #pragma unroll
        for (int q = 0; q < 8; ++q) {
            float4 e4 = er[q], w4 = wr[q];
            acc += e4.x * w4.x + e4.y * w4.y + e4.z * w4.z + e4.w * w4.w;
        }
        P[i] = acc;
    }
}

// ---------------- K2: serial RNN scans — recurrence via __shfl ---------------------
__global__ void k_rnn(const float* __restrict__ P,
                      const float* __restrict__ W_lr, const float* __restrict__ W_rl,
                      const float* __restrict__ h0, __bf16* __restrict__ hcat) {
    __shared__ float Psh[S * 4 * HID];   // 16 KB: [s][bl][j]
    const int t = threadIdx.x;           // 0..63, single wave
    const int dir = blockIdx.x >> 3, bq = blockIdx.x & 7;
    const int bl = t >> 4, j = t & 15;
    const int b = bq * 4 + bl;
    {
        const float4* Pg4 = reinterpret_cast<const float4*>(P);
        float4* Ps4 = reinterpret_cast<float4*>(Psh);
        #pragma unroll
        for (int i = 0; i < 16; ++i) {
            int s = (t >> 4) + 4 * i;
            Ps4[t + 64 * i] = Pg4[dir * 8192 + s * 128 + bq * 16 + (t & 15)];
        }
    }
    const float* Wd = (dir ? W_rl : W_lr) + j * (EMB + HID) + EMB;
    float wh[16];
    #pragma unroll
    for (int q = 0; q < 4; ++q) {
        float4 w4 = *reinterpret_cast<const float4*>(Wd + q * 4);
        wh[q * 4 + 0] = w4.x; wh[q * 4 + 1] = w4.y;
        wh[q * 4 + 2] = w4.z; wh[q * 4 + 3] = w4.w;
    }
    float hcur = h0[j];
    for (int step = 0; step < S; ++step) {
        const int s = dir ? (S - 1 - step) : step;
        hcat[(s * B + b) * 32 + dir * HID + j] = (__bf16)hcur;   // pre-state
        float acc = Psh[s * 64 + bl * 16 + j];
        #pragma unroll
        for (int k = 0; k < HID; ++k)
            acc += wh[k] * __shfl(hcur, (t & 48) + k, 64);
        hcur = tanhf(acc);
    }
}

// ---------------- K3: pass 1 — Wb slice in registers, loop over row-tiles ----------
__global__ void k_pass1(const __bf16* __restrict__ hb, const __bf16* __restrict__ Wb,
                        const float* __restrict__ bias, float* __restrict__ partials) {
    const int cbx = blockIdx.x, rg = blockIdx.y;
    const int wave = threadIdx.x >> 6, lane = threadIdx.x & 63;
    const int lr = lane & 15, kg = lane >> 4;
    const int ttbase = cbx * 16 + wave * 4;
    bf16x8 wfrag[4]; float bc[4];
    #pragma unroll
    for (int q = 0; q < 4; ++q) {
        wfrag[q] = *reinterpret_cast<const bf16x8*>(Wb + ((ttbase + q) * 16 + lr) * 32 + kg * 8);
        bc[q] = bias[(ttbase + q) * 16 + lr];
    }
    __shared__ float red[4][16];
    const f32x4 zero = {0.f, 0.f, 0.f, 0.f};
    for (int rt = rg * RT_PER; rt < rg * RT_PER + RT_PER; ++rt) {
        const int m0 = rt * 16;
        const bf16x8 a = *reinterpret_cast<const bf16x8*>(hb + (m0 + lr) * 32 + kg * 8);
        float s0 = 0.f, s1 = 0.f, s2 = 0.f, s3 = 0.f;
        #pragma unroll
        for (int q = 0; q < 4; ++q) {
            f32x4 d = __builtin_amdgcn_mfma_f32_16x16x32_bf16(a, wfrag[q], zero, 0, 0, 0);
            s0 += __expf(d[0] + bc[q]);
            s1 += __expf(d[1] + bc[q]);
            s2 += __expf(d[2] + bc[q]);
            s3 += __expf(d[3] + bc[q]);
        }
        #pragma unroll
        for (int off = 1; off < 16; off <<= 1) {
            s0 += __shfl_xor(s0, off);
            s1 += __shfl_xor(s1, off);
            s2 += __shfl_xor(s2, off);
            s3 += __shfl_xor(s3, off);
        }
        if (lr == 0) {
            red[wave][kg * 4 + 0] = s0;
            red[wave][kg * 4 + 1] = s1;
            red[wave][kg * 4 + 2] = s2;
            red[wave][kg * 4 + 3] = s3;
        }
        __syncthreads();
        if (threadIdx.x < 16)
            partials[cbx * M + m0 + threadIdx.x] =
                red[0][threadIdx.x] + red[1][threadIdx.x] +
                red[2][threadIdx.x] + red[3][threadIdx.x];
        __syncthreads();
    }
}

// ---------------- K4: reduce partials -> logZ --------------------------------------
__global__ void k_reduce(const float* __restrict__ partials, float* __restrict__ logZ) {
    int r = blockIdx.x * 256 + threadIdx.x;
    float tot = 0.f;
    for (int c = 0; c < NCB; ++c) tot += partials[c * M + r];
    logZ[r] = __logf(tot);
}

// ---------------- K5: pass 2 — DRAIN-FREE long store stream ------------------------
// grid (66,8) = 528 long-lived blocks. Prologue stages EVERYTHING: Wb/bias slice in
// registers, block's 256 hb rows (16 KB) + 256 logZ (1 KB) into LDS. Steady loop
// (16 row-tiles x 3 chunks) has ZERO vmem loads -> vmcnt counts stores only and is
// never waited on: each wave issues 768 store-instrs as one continuous stream
// (hw self-throttles at 63 outstanding), one endpgm drain amortized over all of it.
// This is the structural property the 6.8 TB/s fill has and every prior round lacked.
__global__ __launch_bounds__(256, 4) void k_pass2(
        const __bf16* __restrict__ hb, const __bf16* __restrict__ Wb,
        const float* __restrict__ bias, const float* __restrict__ logZ,
        float* __restrict__ out) {
    __shared__ __bf16 hbs[256 * 32];      // 16 KB: block's 256 rows of hb
    __shared__ float lzs[256];            //  1 KB
    __shared__ float stg[4][16][68];      // 17.4 KB wave-private slabs
    const int cg = blockIdx.x, rg = blockIdx.y;
    const int t = threadIdx.x;
    const int wave = t >> 6, lane = t & 63;
    const int lr = lane & 15, kg = lane >> 4;
    const int c0 = cg * CPG2;
    const int row0 = rg * 256;

    // ---- prologue: ALL global reads ----
    {
        const float4* src = reinterpret_cast<const float4*>(hb + row0 * 32);
        float4* dst = reinterpret_cast<float4*>(hbs);
        #pragma unroll
        for (int i = 0; i < 4; ++i) dst[t + 256 * i] = src[t + 256 * i];
        lzs[t] = logZ[row0 + t];
    }
    bf16x8 wf[CPG2][4];
    float  bc[CPG2][4];
    #pragma unroll
    for (int c = 0; c < CPG2; ++c) {
        const int t0 = (c0 + c) * 16 + wave * 4;
        #pragma unroll
        for (int q = 0; q < 4; ++q) {
            wf[c][q] = *reinterpret_cast<const bf16x8*>(Wb + ((t0 + q) * 16 + lr) * 32 + kg * 8);
            bc[c][q] = bias[(t0 + q) * 16 + lr];
        }
    }
    __syncthreads();   // one-time drain; stores stream uninterrupted from here

    float (*st)[68] = stg[wave];
    const bool guard = (cg == NCG2 - 1);
    const f32x4 zero = {0.f, 0.f, 0.f, 0.f};
    for (int rtl = 0; rtl < RTPB; ++rtl) {
        const int m0 = row0 + rtl * 16;
        const bf16x8 a = *reinterpret_cast<const bf16x8*>(&hbs[(rtl * 16 + lr) * 32 + kg * 8]);
        const float4 lz4 = *reinterpret_cast<const float4*>(&lzs[rtl * 16 + kg * 4]);
        const float lzr[4] = { lz4.x, lz4.y, lz4.z, lz4.w };
        #pragma unroll
        for (int c = 0; c < CPG2; ++c) {
            #pragma unroll
            for (int q = 0; q < 4; ++q) {
                f32x4 d = __builtin_amdgcn_mfma_f32_16x16x32_bf16(a, wf[c][q], zero, 0, 0, 0);
                const int cl = q * 16 + lr;
                #pragma unroll
                for (int r = 0; r < 4; ++r)
                    st[kg * 4 + r][cl] = d[r] + bc[c][q] - lzr[r];
            }
            asm volatile("s_waitcnt lgkmcnt(0)" ::: "memory");   // LDS fence only
            __builtin_amdgcn_sched_barrier(0);                   // rule 18
            const int cb0 = (c0 + c) * 256 + wave * 64;
            const int vcol = cb0 + lane;
            float* p = out + (size_t)m0 * V + vcol;
            if (!guard) {
                #pragma unroll
                for (int r = 0; r < 16; ++r)
                    p[(size_t)r * V] = st[r][lane];
            } else {
                #pragma unroll
                for (int r = 0; r < 16; ++r)
                    if (vcol < V) p[(size_t)r * V] = st[r][lane];
            }
        }
    }
}

extern "C" void kernel_launch(void* const* d_in, const int* in_sizes, int n_in,
                              void* d_out, int out_size, void* d_ws, size_t ws_size,
                              hipStream_t stream) {
    const int*   idx       = (const int*)d_in[0];
    const float* embedding = (const float*)d_in[1];
    const float* W_lr      = (const float*)d_in[2];
    const float* b_lr      = (const float*)d_in[3];
    const float* W_rl      = (const float*)d_in[4];
    const float* b_rl      = (const float*)d_in[5];
    const float* W_ho      = (const float*)d_in[6];
    const float* b_ho      = (const float*)d_in[7];
    const float* h0        = (const float*)d_in[8];
    float* out = (float*)d_out;

    char* ws = (char*)d_ws;
    size_t off = 0;
    __bf16* Wb      = (__bf16*)(ws + off); off += (size_t)VP5 * EMB * 2;   // 3,244,032
    float*  bias    = (float*)(ws + off);  off += (size_t)VP5 * 4;         //   202,752
    __bf16* hb      = (__bf16*)(ws + off); off += (size_t)M * 32 * 2;      //   131,072
    float*  P       = (float*)(ws + off);  off += (size_t)2 * M * HID * 4; //   262,144
    float*  partials= (float*)(ws + off);  off += (size_t)NCB * M * 4;     // 1,613,824
    float*  logZ    = (float*)(ws + off);  off += (size_t)M * 4;           //     8,192

    k_prep<<<PREP_BLOCKS + 256, 256, 0, stream>>>(W_ho, b_ho, idx, embedding,
                                                  W_lr, b_lr, W_rl, b_rl, Wb, bias, P);
    k_rnn<<<16, 64, 0, stream>>>(P, W_lr, W_rl, h0, hb);
    k_pass1<<<dim3(NCB, NRG), 256, 0, stream>>>(hb, Wb, bias, partials);
    k_reduce<<<8, 256, 0, stream>>>(partials, logZ);
    k_pass2<<<dim3(NCG2, 8), 256, 0, stream>>>(hb, Wb, bias, logZ, out);
}

// Round 17
// 183.458 us; speedup vs baseline: 1.1069x; 1.1069x over previous
//
#include <hip/hip_runtime.h>
#include <hip/hip_bf16.h>

#define S 64
#define B 32
#define HID 16
#define EMB 32
#define V 50257
#define NCB 197                 // pass1 column blocks of 256 cols (50432 scanned)
#define NPW (NCB*4)             // 788 per-wave partial streams
#define NCG2 16                 // pass2 column groups
#define CPG2 13                 // 256-col chunks per group
#define VP5 (NCG2*CPG2*256)     // 53248 padded cols
#define M 2048                  // S*B rows
#define PREP_BLOCKS (VP5*EMB/256)   // 6656 exactly
#define NRG 8                   // row groups for pass1
#define RT_PER (128/NRG)

using bf16x8 = __attribute__((ext_vector_type(8))) __bf16;
using f32x4  = __attribute__((ext_vector_type(4))) float;

// ---------------- K1: fused prep (R13 verbatim) ------------------------------------
__global__ void k_prep(const float* __restrict__ W_ho, const float* __restrict__ b_ho,
                       const int* __restrict__ idx, const float* __restrict__ emb,
                       const float* __restrict__ W_lr, const float* __restrict__ b_lr,
                       const float* __restrict__ W_rl, const float* __restrict__ b_rl,
                       __bf16* __restrict__ Wb, float* __restrict__ bias,
                       float* __restrict__ P) {
    const int bx = blockIdx.x;
    if (bx < PREP_BLOCKS) {
        int i = bx * 256 + threadIdx.x;          // < VP5*EMB exactly
        if (i < VP5) bias[i] = (i < V) ? b_ho[i] : -1e30f;
        int v = i >> 5;
        Wb[i] = (v < V) ? (__bf16)W_ho[i] : (__bf16)0.f;
    } else {
        int i = (bx - PREP_BLOCKS) * 256 + threadIdx.x;   // 0..65535
        const int dir = i >> 15, r = i & 32767, m = r >> 4, j = r & 15;
        const float* W  = dir ? W_rl : W_lr;
        const float* bb = dir ? b_rl : b_lr;
        const int tok = idx[m];
        const float4* er = reinterpret_cast<const float4*>(emb + (size_t)tok * EMB);
        const float4* wr = reinterpret_cast<const float4*>(W + j * (EMB + HID));
        float acc = bb[j];
        #pragma unroll
        for (int q = 0; q < 8; ++q) {
            float4 e4 = er[q], w4 = wr[q];
            acc += e4.x * w4.x + e4.y * w4.y + e4.z * w4.z + e4.w * w4.w;
        }
        P[i] = acc;
    }
}

// ---------------- K2: serial RNN scans (R13 verbatim) ------------------------------
__global__ void k_rnn(const float* __restrict__ P,
                      const float* __restrict__ W_lr, const float* __restrict__ W_rl,
                      const float* __restrict__ h0, __bf16* __restrict__ hcat) {
    __shared__ float Psh[S * 4 * HID];   // 16 KB: [s][bl][j]
    const int t = threadIdx.x;           // 0..63, single wave
    const int dir = blockIdx.x >> 3, bq = blockIdx.x & 7;
    const int bl = t >> 4, j = t & 15;
    const int b = bq * 4 + bl;
    {
        const float4* Pg4 = reinterpret_cast<const float4*>(P);
        float4* Ps4 = reinterpret_cast<float4*>(Psh);
        #pragma unroll
        for (int i = 0; i < 16; ++i) {
            int s = (t >> 4) + 4 * i;
            Ps4[t + 64 * i] = Pg4[dir * 8192 + s * 128 + bq * 16 + (t & 15)];
        }
    }
    const float* Wd = (dir ? W_rl : W_lr) + j * (EMB + HID) + EMB;
    float wh[16];
    #pragma unroll
    for (int q = 0; q < 4; ++q) {
        float4 w4 = *reinterpret_cast<const float4*>(Wd + q * 4);
        wh[q * 4 + 0] = w4.x; wh[q * 4 + 1] = w4.y;
        wh[q * 4 + 2] = w4.z; wh[q * 4 + 3] = w4.w;
    }
    float hcur = h0[j];
    for (int step = 0; step < S; ++step) {
        const int s = dir ? (S - 1 - step) : step;
        hcat[(s * B + b) * 32 + dir * HID + j] = (__bf16)hcur;   // pre-state
        float acc = Psh[s * 64 + bl * 16 + j];
        #pragma unroll
        for (int k = 0; k < HID; ++k)
            acc += wh[k] * __shfl(hcur, (t & 48) + k, 64);
        hcur = tanhf(acc);
    }
}

// ---------------- K3: pass 1 — swapped-MFMA, barrier-free (R12-phase1 structure) ---
// Wave owns 4 col-tiles; mfma(W,h) puts row m in lane&15, vocab in (kg,reg) ->
// per-lane exp accumulation, 2 shfl_xor to fold kg, 16-lane store. No LDS/barriers.
__global__ void k_pass1(const __bf16* __restrict__ hb, const __bf16* __restrict__ Wb,
                        const float* __restrict__ bias, float* __restrict__ partials) {
    const int cbx = blockIdx.x, rg = blockIdx.y;
    const int wave = threadIdx.x >> 6, lane = threadIdx.x & 63;
    const int lr = lane & 15, kg = lane >> 4;
    const int ttbase = cbx * 16 + wave * 4;
    bf16x8 wfrag[4]; f32x4 b4[4];
    #pragma unroll
    for (int q = 0; q < 4; ++q) {
        wfrag[q] = *reinterpret_cast<const bf16x8*>(Wb + ((ttbase + q) * 16 + lr) * 32 + kg * 8);
        b4[q] = *reinterpret_cast<const f32x4*>(bias + (ttbase + q) * 16 + kg * 4);
    }
    const int pw = cbx * 4 + wave;
    const f32x4 zero = {0.f, 0.f, 0.f, 0.f};
    for (int rt = rg * RT_PER; rt < rg * RT_PER + RT_PER; ++rt) {
        const int m0 = rt * 16;
        const bf16x8 a = *reinterpret_cast<const bf16x8*>(hb + (m0 + lr) * 32 + kg * 8);
        float s = 0.f;
        #pragma unroll
        for (int q = 0; q < 4; ++q) {
            f32x4 d = __builtin_amdgcn_mfma_f32_16x16x32_bf16(wfrag[q], a, zero, 0, 0, 0);
            s += __expf(d[0] + b4[q][0]) + __expf(d[1] + b4[q][1]) +
                 __expf(d[2] + b4[q][2]) + __expf(d[3] + b4[q][3]);
        }
        s += __shfl_xor(s, 16);          // fold the 4 kg groups (vocab slices)
        s += __shfl_xor(s, 32);
        if (lane < 16) partials[pw * M + m0 + lane] = s;
    }
}

// ---------------- K4: pass 2 — R13 verbatim (folded logZ over 788 partials) --------
__device__ __forceinline__ void p2_load(const __bf16* __restrict__ Wb,
                                        const float* __restrict__ bias,
                                        int chunk, int wave, int lr, int kg,
                                        bf16x8* wf, float* bc) {
    const int t0 = chunk * 16 + wave * 4;
    #pragma unroll
    for (int q = 0; q < 4; ++q) {
        wf[q] = *reinterpret_cast<const bf16x8*>(Wb + ((t0 + q) * 16 + lr) * 32 + kg * 8);
        bc[q] = bias[(t0 + q) * 16 + lr];
    }
}

template <bool GUARD>
__device__ __forceinline__ void p2_cs(const bf16x8* wf, const float* bc, bf16x8 a,
                                      const float* lzr, int chunk, int wave,
                                      int lane, int lr, int kg, int m0,
                                      float* __restrict__ out, float (*st)[68]) {
    const f32x4 zero = {0.f, 0.f, 0.f, 0.f};
    #pragma unroll
    for (int q = 0; q < 4; ++q) {
        f32x4 d = __builtin_amdgcn_mfma_f32_16x16x32_bf16(a, wf[q], zero, 0, 0, 0);
        const int cl = q * 16 + lr;
        #pragma unroll
        for (int r = 0; r < 4; ++r)
            st[kg * 4 + r][cl] = d[r] + bc[q] - lzr[r];
    }
    asm volatile("s_waitcnt lgkmcnt(0)" ::: "memory");   // wave-internal fence
    __builtin_amdgcn_sched_barrier(0);                   // rule 18
    const int cb0 = chunk * 256 + wave * 64;
    const int vcol = cb0 + lane;
    float* p = out + (size_t)m0 * V + vcol;
    #pragma unroll
    for (int r = 0; r < 16; ++r) {
        if (!GUARD || vcol < V)
            p[(size_t)r * V] = st[r][lane];
    }
}

__global__ __launch_bounds__(256, 6) void k_pass2(
        const __bf16* __restrict__ hb, const __bf16* __restrict__ Wb,
        const float* __restrict__ bias, const float* __restrict__ partials,
        float* __restrict__ out) {
    __shared__ float red[16][17];
    __shared__ float lzsh[16];
    __shared__ float stg[4][16][68];      // single-buffered wave-private slabs
    const int cg = blockIdx.x, rt = blockIdx.y;
    const int t = threadIdx.x;
    const int m0 = rt * 16;
    {
        const int row = t & 15, cch = t >> 4;
        float p = 0.f;
        for (int c = cch; c < NPW; c += 16) p += partials[c * M + m0 + row];
        red[cch][row] = p;
        __syncthreads();
        if (t < 16) {
            float tot = 0.f;
            #pragma unroll
            for (int k = 0; k < 16; ++k) tot += red[k][t];
            lzsh[t] = __logf(tot);
        }
        __syncthreads();
    }
    const int wave = t >> 6, lane = t & 63;
    const int lr = lane & 15, kg = lane >> 4;
    const bf16x8 a = *reinterpret_cast<const bf16x8*>(hb + (m0 + lr) * 32 + kg * 8);
    float lzr[4];
    #pragma unroll
    for (int r = 0; r < 4; ++r) lzr[r] = lzsh[kg * 4 + r];
    float (*st)[68] = stg[wave];
    const int c0 = cg * CPG2;             // chunks c0 .. c0+12

    bf16x8 wfA[4], wfB[4];
    float bcA[4], bcB[4];
    p2_load(Wb, bias, c0, wave, lr, kg, wfA, bcA);
    if (cg < 15) {
        for (int g = 0; g < 6; ++g) {
            p2_load(Wb, bias, c0 + 2 * g + 1, wave, lr, kg, wfB, bcB);
            p2_cs<false>(wfA, bcA, a, lzr, c0 + 2 * g, wave, lane, lr, kg, m0, out, st);
            p2_load(Wb, bias, c0 + 2 * g + 2, wave, lr, kg, wfA, bcA);
            p2_cs<false>(wfB, bcB, a, lzr, c0 + 2 * g + 1, wave, lane, lr, kg, m0, out, st);
        }
        p2_cs<false>(wfA, bcA, a, lzr, c0 + 12, wave, lane, lr, kg, m0, out, st);
    } else {
        for (int g = 0; g < 6; ++g) {
            p2_load(Wb, bias, c0 + 2 * g + 1, wave, lr, kg, wfB, bcB);
            p2_cs<true>(wfA, bcA, a, lzr, c0 + 2 * g, wave, lane, lr, kg, m0, out, st);
            p2_load(Wb, bias, c0 + 2 * g + 2, wave, lr, kg, wfA, bcA);
            p2_cs<true>(wfB, bcB, a, lzr, c0 + 2 * g + 1, wave, lane, lr, kg, m0, out, st);
        }
        p2_cs<true>(wfA, bcA, a, lzr, c0 + 12, wave, lane, lr, kg, m0, out, st);
    }
}

extern "C" void kernel_launch(void* const* d_in, const int* in_sizes, int n_in,
                              void* d_out, int out_size, void* d_ws, size_t ws_size,
                              hipStream_t stream) {
    const int*   idx       = (const int*)d_in[0];
    const float* embedding = (const float*)d_in[1];
    const float* W_lr      = (const float*)d_in[2];
    const float* b_lr      = (const float*)d_in[3];
    const float* W_rl      = (const float*)d_in[4];
    const float* b_rl      = (const float*)d_in[5];
    const float* W_ho      = (const float*)d_in[6];
    const float* b_ho      = (const float*)d_in[7];
    const float* h0        = (const float*)d_in[8];
    float* out = (float*)d_out;

    char* ws = (char*)d_ws;
    size_t off = 0;
    __bf16* Wb      = (__bf16*)(ws + off); off += (size_t)VP5 * EMB * 2;   // 3,407,872
    float*  bias    = (float*)(ws + off);  off += (size_t)VP5 * 4;         //   212,992
    __bf16* hb      = (__bf16*)(ws + off); off += (size_t)M * 32 * 2;      //   131,072
    float*  P       = (float*)(ws + off);  off += (size_t)2 * M * HID * 4; //   262,144
    float*  partials= (float*)(ws + off);  off += (size_t)NPW * M * 4;     // 6,455,296

    k_prep<<<PREP_BLOCKS + 256, 256, 0, stream>>>(W_ho, b_ho, idx, embedding,
                                                  W_lr, b_lr, W_rl, b_rl, Wb, bias, P);
    k_rnn<<<16, 64, 0, stream>>>(P, W_lr, W_rl, h0, hb);
    k_pass1<<<dim3(NCB, NRG), 256, 0, stream>>>(hb, Wb, bias, partials);
    k_pass2<<<dim3(NCG2, 128), 256, 0, stream>>>(hb, Wb, bias, partials, out);
}

// Round 18
// 180.651 us; speedup vs baseline: 1.1241x; 1.0155x over previous
//
#include <hip/hip_runtime.h>
#include <hip/hip_bf16.h>

#define S 64
#define B 32
#define HID 16
#define EMB 32
#define V 50257
#define NCB 197                 // pass1 column blocks of 256 cols (50432 scanned)
#define NCG2 16                 // pass2 column groups
#define CPG2 13                 // 256-col chunks per group
#define VP5 (NCG2*CPG2*256)     // 53248 padded cols
#define M 2048                  // S*B rows
#define PREP_BLOCKS (VP5*EMB/256)   // 6656 exactly
#define NRG 8                   // row groups for pass1
#define RT_PER (128/NRG)

using bf16x8 = __attribute__((ext_vector_type(8))) __bf16;
using f32x4  = __attribute__((ext_vector_type(4))) float;

// ---------------- K1: fused prep ---------------------------------------------------
__global__ void k_prep(const float* __restrict__ W_ho, const float* __restrict__ b_ho,
                       const int* __restrict__ idx, const float* __restrict__ emb,
                       const float* __restrict__ W_lr, const float* __restrict__ b_lr,
                       const float* __restrict__ W_rl, const float* __restrict__ b_rl,
                       __bf16* __restrict__ Wb, float* __restrict__ bias,
                       float* __restrict__ P) {
    const int bx = blockIdx.x;
    if (bx < PREP_BLOCKS) {
        int i = bx * 256 + threadIdx.x;          // < VP5*EMB exactly
        if (i < VP5) bias[i] = (i < V) ? b_ho[i] : -1e30f;
        int v = i >> 5;
        Wb[i] = (v < V) ? (__bf16)W_ho[i] : (__bf16)0.f;
    } else {
        int i = (bx - PREP_BLOCKS) * 256 + threadIdx.x;   // 0..65535
        const int dir = i >> 15, r = i & 32767, m = r >> 4, j = r & 15;
        const float* W  = dir ? W_rl : W_lr;
        const float* bb = dir ? b_rl : b_lr;
        const int tok = idx[m];
        const float4* er = reinterpret_cast<const float4*>(emb + (size_t)tok * EMB);
        const float4* wr = reinterpret_cast<const float4*>(W + j * (EMB + HID));
        float acc = bb[j];
        #pragma unroll
        for (int q = 0; q < 8; ++q) {
            float4 e4 = er[q], w4 = wr[q];
            acc += e4.x * w4.x + e4.y * w4.y + e4.z * w4.z + e4.w * w4.w;
        }
        P[i] = acc;
    }
}

// ---------------- K2: serial RNN scans — recurrence via __shfl ---------------------
__global__ void k_rnn(const float* __restrict__ P,
                      const float* __restrict__ W_lr, const float* __restrict__ W_rl,
                      const float* __restrict__ h0, __bf16* __restrict__ hcat) {
    __shared__ float Psh[S * 4 * HID];   // 16 KB: [s][bl][j]
    const int t = threadIdx.x;           // 0..63, single wave
    const int dir = blockIdx.x >> 3, bq = blockIdx.x & 7;
    const int bl = t >> 4, j = t & 15;
    const int b = bq * 4 + bl;
    {
        const float4* Pg4 = reinterpret_cast<const float4*>(P);
        float4* Ps4 = reinterpret_cast<float4*>(Psh);
        #pragma unroll
        for (int i = 0; i < 16; ++i) {
            int s = (t >> 4) + 4 * i;
            Ps4[t + 64 * i] = Pg4[dir * 8192 + s * 128 + bq * 16 + (t & 15)];
        }
    }
    const float* Wd = (dir ? W_rl : W_lr) + j * (EMB + HID) + EMB;
    float wh[16];
    #pragma unroll
    for (int q = 0; q < 4; ++q) {
        float4 w4 = *reinterpret_cast<const float4*>(Wd + q * 4);
        wh[q * 4 + 0] = w4.x; wh[q * 4 + 1] = w4.y;
        wh[q * 4 + 2] = w4.z; wh[q * 4 + 3] = w4.w;
    }
    float hcur = h0[j];
    for (int step = 0; step < S; ++step) {
        const int s = dir ? (S - 1 - step) : step;
        hcat[(s * B + b) * 32 + dir * HID + j] = (__bf16)hcur;   // pre-state
        float acc = Psh[s * 64 + bl * 16 + j];
        #pragma unroll
        for (int k = 0; k < HID; ++k)
            acc += wh[k] * __shfl(hcur, (t & 48) + k, 64);
        hcur = tanhf(acc);
    }
}

// ---------------- K3: pass 1 — Wb slice in registers, loop over row-tiles ----------
__global__ void k_pass1(const __bf16* __restrict__ hb, const __bf16* __restrict__ Wb,
                        const float* __restrict__ bias, float* __restrict__ partials) {
    const int cbx = blockIdx.x, rg = blockIdx.y;
    const int wave = threadIdx.x >> 6, lane = threadIdx.x & 63;
    const int lr = lane & 15, kg = lane >> 4;
    const int ttbase = cbx * 16 + wave * 4;
    bf16x8 wfrag[4]; float bc[4];
    #pragma unroll
    for (int q = 0; q < 4; ++q) {
        wfrag[q] = *reinterpret_cast<const bf16x8*>(Wb + ((ttbase + q) * 16 + lr) * 32 + kg * 8);
        bc[q] = bias[(ttbase + q) * 16 + lr];
    }
    __shared__ float red[4][16];
    const f32x4 zero = {0.f, 0.f, 0.f, 0.f};
    for (int rt = rg * RT_PER; rt < rg * RT_PER + RT_PER; ++rt) {
        const int m0 = rt * 16;
        const bf16x8 a = *reinterpret_cast<const bf16x8*>(hb + (m0 + lr) * 32 + kg * 8);
        float s0 = 0.f, s1 = 0.f, s2 = 0.f, s3 = 0.f;
        #pragma unroll
        for (int q = 0; q < 4; ++q) {
            f32x4 d = __builtin_amdgcn_mfma_f32_16x16x32_bf16(a, wfrag[q], zero, 0, 0, 0);
            s0 += __expf(d[0] + bc[q]);
            s1 += __expf(d[1] + bc[q]);
            s2 += __expf(d[2] + bc[q]);
            s3 += __expf(d[3] + bc[q]);
        }
        #pragma unroll
        for (int off = 1; off < 16; off <<= 1) {
            s0 += __shfl_xor(s0, off);
            s1 += __shfl_xor(s1, off);
            s2 += __shfl_xor(s2, off);
            s3 += __shfl_xor(s3, off);
        }
        if (lr == 0) {
            red[wave][kg * 4 + 0] = s0;
            red[wave][kg * 4 + 1] = s1;
            red[wave][kg * 4 + 2] = s2;
            red[wave][kg * 4 + 3] = s3;
        }
        __syncthreads();
        if (threadIdx.x < 16)
            partials[cbx * M + m0 + threadIdx.x] =
                red[0][threadIdx.x] + red[1][threadIdx.x] +
                red[2][threadIdx.x] + red[3][threadIdx.x];
        __syncthreads();
    }
}

// ---------------- K4: pass 2 — high-occupancy single-buffer streaming --------------
__device__ __forceinline__ void p2_load(const __bf16* __restrict__ Wb,
                                        const float* __restrict__ bias,
                                        int chunk, int wave, int lr, int kg,
                                        bf16x8* wf, float* bc) {
    const int t0 = chunk * 16 + wave * 4;
    #pragma unroll
    for (int q = 0; q < 4; ++q) {
        wf[q] = *reinterpret_cast<const bf16x8*>(Wb + ((t0 + q) * 16 + lr) * 32 + kg * 8);
        bc[q] = bias[(t0 + q) * 16 + lr];
    }
}

template <bool GUARD>
__device__ __forceinline__ void p2_cs(const bf16x8* wf, const float* bc, bf16x8 a,
                                      const float* lzr, int chunk, int wave,
                                      int lane, int lr, int kg, int m0,
                                      float* __restrict__ out, float (*st)[68]) {
    const f32x4 zero = {0.f, 0.f, 0.f, 0.f};
    #pragma unroll
    for (int q = 0; q < 4; ++q) {
        f32x4 d = __builtin_amdgcn_mfma_f32_16x16x32_bf16(a, wf[q], zero, 0, 0, 0);
        const int cl = q * 16 + lr;
        #pragma unroll
        for (int r = 0; r < 4; ++r)
            st[kg * 4 + r][cl] = d[r] + bc[q] - lzr[r];
    }
    asm volatile("s_waitcnt lgkmcnt(0)" ::: "memory");   // wave-internal fence
    __builtin_amdgcn_sched_barrier(0);                   // rule 18
    const int cb0 = chunk * 256 + wave * 64;
    const int vcol = cb0 + lane;
    float* p = out + (size_t)m0 * V + vcol;
    #pragma unroll
    for (int r = 0; r < 16; ++r) {
        if (!GUARD || vcol < V)
            p[(size_t)r * V] = st[r][lane];
    }
}

__global__ __launch_bounds__(256, 6) void k_pass2(
        const __bf16* __restrict__ hb, const __bf16* __restrict__ Wb,
        const float* __restrict__ bias, const float* __restrict__ partials,
        float* __restrict__ out) {
    __shared__ float red[16][17];
    __shared__ float lzsh[16];
    __shared__ float stg[4][16][68];      // single-buffered wave-private slabs
    const int cg = blockIdx.x, rt = blockIdx.y;
    const int t = threadIdx.x;
    const int m0 = rt * 16;
    {
        const int row = t & 15, cch = t >> 4;
        float p = 0.f;
        for (int c = cch; c < NCB; c += 16) p += partials[c * M + m0 + row];
        red[cch][row] = p;
        __syncthreads();
        if (t < 16) {
            float tot = 0.f;
            #pragma unroll
            for (int k = 0; k < 16; ++k) tot += red[k][t];
            lzsh[t] = __logf(tot);
        }
        __syncthreads();
    }
    const int wave = t >> 6, lane = t & 63;
    const int lr = lane & 15, kg = lane >> 4;
    const bf16x8 a = *reinterpret_cast<const bf16x8*>(hb + (m0 + lr) * 32 + kg * 8);
    float lzr[4];
    #pragma unroll
    for (int r = 0; r < 4; ++r) lzr[r] = lzsh[kg * 4 + r];
    float (*st)[68] = stg[wave];
    const int c0 = cg * CPG2;             // chunks c0 .. c0+12

    bf16x8 wfA[4], wfB[4];
    float bcA[4], bcB[4];
    p2_load(Wb, bias, c0, wave, lr, kg, wfA, bcA);
    if (cg < 15) {
        for (int g = 0; g < 6; ++g) {
            p2_load(Wb, bias, c0 + 2 * g + 1, wave, lr, kg, wfB, bcB);
            p2_cs<false>(wfA, bcA, a, lzr, c0 + 2 * g, wave, lane, lr, kg, m0, out, st);
            p2_load(Wb, bias, c0 + 2 * g + 2, wave, lr, kg, wfA, bcA);
            p2_cs<false>(wfB, bcB, a, lzr, c0 + 2 * g + 1, wave, lane, lr, kg, m0, out, st);
        }
        p2_cs<false>(wfA, bcA, a, lzr, c0 + 12, wave, lane, lr, kg, m0, out, st);
    } else {
        for (int g = 0; g < 6; ++g) {
            p2_load(Wb, bias, c0 + 2 * g + 1, wave, lr, kg, wfB, bcB);
            p2_cs<true>(wfA, bcA, a, lzr, c0 + 2 * g, wave, lane, lr, kg, m0, out, st);
            p2_load(Wb, bias, c0 + 2 * g + 2, wave, lr, kg, wfA, bcA);
            p2_cs<true>(wfB, bcB, a, lzr, c0 + 2 * g + 1, wave, lane, lr, kg, m0, out, st);
        }
        p2_cs<true>(wfA, bcA, a, lzr, c0 + 12, wave, lane, lr, kg, m0, out, st);
    }
}

extern "C" void kernel_launch(void* const* d_in, const int* in_sizes, int n_in,
                              void* d_out, int out_size, void* d_ws, size_t ws_size,
                              hipStream_t stream) {
    const int*   idx       = (const int*)d_in[0];
    const float* embedding = (const float*)d_in[1];
    const float* W_lr      = (const float*)d_in[2];
    const float* b_lr      = (const float*)d_in[3];
    const float* W_rl      = (const float*)d_in[4];
    const float* b_rl      = (const float*)d_in[5];
    const float* W_ho      = (const float*)d_in[6];
    const float* b_ho      = (const float*)d_in[7];
    const float* h0        = (const float*)d_in[8];
    float* out = (float*)d_out;

    char* ws = (char*)d_ws;
    size_t off = 0;
    __bf16* Wb      = (__bf16*)(ws + off); off += (size_t)VP5 * EMB * 2;   // 3,407,872
    float*  bias    = (float*)(ws + off);  off += (size_t)VP5 * 4;         //   212,992
    __bf16* hb      = (__bf16*)(ws + off); off += (size_t)M * 32 * 2;      //   131,072
    float*  P       = (float*)(ws + off);  off += (size_t)2 * M * HID * 4; //   262,144
    float*  partials= (float*)(ws + off);  off += (size_t)NCB * M * 4;     // 1,613,824

    k_prep<<<PREP_BLOCKS + 256, 256, 0, stream>>>(W_ho, b_ho, idx, embedding,
                                                  W_lr, b_lr, W_rl, b_rl, Wb, bias, P);
    k_rnn<<<16, 64, 0, stream>>>(P, W_lr, W_rl, h0, hb);
    k_pass1<<<dim3(NCB, NRG), 256, 0, stream>>>(hb, Wb, bias, partials);
    k_pass2<<<dim3(NCG2, 128), 256, 0, stream>>>(hb, Wb, bias, partials, out);
}